// Round 5
// baseline (3670.762 us; speedup 1.0000x reference)
//
#include <hip/hip_runtime.h>
#include <cstddef>

#define B_    4
#define T_    16384
#define WD_   128
#define SD_   512
#define FOUT_ 14337
#define NL_   20
#define NTOT_ (B_*FOUT_)                       // 57348
#define NT16_ ((NTOT_+15)/16)                  // 3585 tiles
#define BSTR_ ((size_t)T_*WD_)                 // acts per-b stride (shorts)
#define LSTR_ ((size_t)B_*T_*WD_)              // acts per-l stride (shorts)

typedef float f32x4 __attribute__((ext_vector_type(4)));
typedef short bf16x8 __attribute__((ext_vector_type(8)));

// ---- static device buffers ----
__device__ float g_x0[(size_t)B_*T_*WD_];
__device__ float g_x1[(size_t)B_*T_*WD_];
__device__ unsigned short g_xB0[(size_t)B_*T_*WD_];
__device__ unsigned short g_xB1[(size_t)B_*T_*WD_];
__device__ unsigned short g_WdF0[(size_t)NL_*256*128];
__device__ unsigned short g_WdF1[(size_t)NL_*256*128];
__device__ unsigned short g_WrF[(size_t)NL_*128*128];
__device__ unsigned short g_WsF[(size_t)512*2560];
__device__ unsigned short g_W1F[(size_t)512*512];
__device__ unsigned short g_W2F[(size_t)256*512];
__device__ float g_bssum[512];
__device__ unsigned short g_actsF[(size_t)NL_*B_*T_*WD_];     // frag layout per (l,b), K=128
__device__ unsigned short g_skipF[(size_t)NT16_*16*512];      // frag layout rows n, K=512
__device__ unsigned short g_h1F [(size_t)NT16_*16*512];

// skipStart per layer = Tout_l - FOUT
__constant__ int d_OFF[NL_] = {2046,2044,2040,2032,2016,1984,1920,1792,1536,1024,
                               1023,1021,1017,1009, 993, 961, 897, 769, 513,   1};

__device__ __forceinline__ unsigned short f2bf(float f){
  unsigned u = __float_as_uint(f);
  u += 0x7FFF + ((u >> 16) & 1u);
  return (unsigned short)(u >> 16);
}
__device__ __forceinline__ float sigm_(float x){ return 1.0f/(1.0f+__expf(-x)); }
__device__ __forceinline__ float tanh_(float x){ return 1.0f - 2.0f/(__expf(2.0f*x)+1.0f); }
__device__ __forceinline__ f32x4 MFMA(bf16x8 a, bf16x8 b, f32x4 c){
  return __builtin_amdgcn_mfma_f32_16x16x32_bf16(a, b, c, 0, 0, 0);
}
// fragment-layout address (shorts), valid for A (row=m) and B (row=n); K mult of 32
__device__ __forceinline__ size_t fragAddr(int row, int k, int K){
  return (size_t)(row>>4)*((K>>5)*512) + (size_t)(k>>5)*512 + (size_t)((k>>3)&3)*128
       + (size_t)(row&15)*8 + (size_t)(k&7);
}

// ---------------- weight conversion ----------------
// Wd [L][256 o][128 c][2 tap] -> WdF0/WdF1 frag layout rows l*256+o, K=128
__global__ void cvt_wd(const float* __restrict__ Wd){
  int i = blockIdx.x*256 + threadIdx.x;
  if (i >= NL_*256*16) return;
  int row = i >> 4, c0 = (i & 15)*8;
  const float* s = Wd + ((size_t)row*128 + c0)*2;
  unsigned short u0[8], u1[8];
#pragma unroll
  for (int j=0;j<8;j++){ u0[j]=f2bf(s[2*j]); u1[j]=f2bf(s[2*j+1]); }
  size_t a = fragAddr(row, c0, 128);
  *(uint4*)((void*)(g_WdF0 + a)) = *(const uint4*)((const void*)u0);
  *(uint4*)((void*)(g_WdF1 + a)) = *(const uint4*)((const void*)u1);
}
// generic row-major [M][K] fp32 -> frag bf16. which: 0=Wr(2560x128) 1=W1(512x512) 2=W2(256x512)
__global__ void cvt_rm(const float* __restrict__ src, int which, int M, int K){
  int i = blockIdx.x*256 + threadIdx.x;
  if (i >= M*(K>>3)) return;
  int row = i / (K>>3), k0 = (i % (K>>3))*8;
  const float* s = src + (size_t)row*K + k0;
  unsigned short u[8];
#pragma unroll
  for (int j=0;j<8;j++) u[j]=f2bf(s[j]);
  unsigned short* dst = (which==0)?g_WrF:(which==1)?g_W1F:g_W2F;
  *(uint4*)((void*)(dst + fragAddr(row, k0, K))) = *(const uint4*)((const void*)u);
}
// Ws [L][512 o][128 c] -> WsF frag rows o, K=2560 (k=l*128+c)
__global__ void cvt_ws(const float* __restrict__ Ws){
  int i = blockIdx.x*256 + threadIdx.x;
  if (i >= NL_*512*16) return;
  int l = i >> 13, rem = i & 8191;
  int o = rem >> 4, c0 = (rem & 15)*8;
  const float* s = Ws + ((size_t)(l*512+o))*128 + c0;
  unsigned short u[8];
#pragma unroll
  for (int j=0;j<8;j++) u[j]=f2bf(s[j]);
  *(uint4*)((void*)(g_WsF + fragAddr(o, l*128 + c0, 2560))) = *(const uint4*)((const void*)u);
}
__global__ void bssum_k(const float* __restrict__ bs){
  int o = threadIdx.x;
  float s = 0.f;
  for (int l=0;l<NL_;l++) s += bs[l*512 + o];
  g_bssum[o] = s;
}

// ---------------- embedding: x0 fp32 + xB0 bf16 mirror ----------------
__global__ void embed_kernel(const int* __restrict__ y, const float* __restrict__ embed){
  int gid = blockIdx.x*256 + threadIdx.x;
  int bt  = gid >> 5;
  int c4  = gid & 31;
  if (bt < B_*T_){
    int idx = y[bt];
    float4 v = ((const float4*)embed)[(size_t)idx*32 + c4];
    ((float4*)g_x0)[(size_t)bt*32 + c4] = v;
    ushort4 p; p.x=f2bf(v.x); p.y=f2bf(v.y); p.z=f2bf(v.z); p.w=f2bf(v.w);
    *(ushort4*)((void*)(g_xB0 + (size_t)bt*128 + c4*4)) = p;
  }
}

// ---------------- fused layer, zero-LDS ----------------
// 256 threads = 4 waves; block tile: 64 time positions, all 256 in_act rows.
__global__ __launch_bounds__(256,2) void layer_frag(
    int swap, int l, int d, int Tout,
    const float* __restrict__ bd_l, const float* __restrict__ br_l)
{
  const float* __restrict__ xin  = swap ? g_x1 : g_x0;
  float* __restrict__       xout = swap ? g_x0 : g_x1;
  const unsigned short* __restrict__ xbin  = swap ? g_xB1 : g_xB0;
  unsigned short* __restrict__       xbout = swap ? g_xB0 : g_xB1;
  const unsigned short* __restrict__ Wd0 = g_WdF0 + (size_t)l*32768;
  const unsigned short* __restrict__ Wd1 = g_WdF1 + (size_t)l*32768;
  const unsigned short* __restrict__ WrF = g_WrF  + (size_t)l*16384;

  const int tid = threadIdx.x;
  const int w   = tid >> 6;
  const int lane= tid & 63;
  const int q   = lane >> 4;
  const int ln  = lane & 15;
  const int b   = blockIdx.y;
  const int t0  = blockIdx.x*64;
  const int ntv = min(64, Tout - t0);
  unsigned short* __restrict__ actsF = g_actsF + (size_t)l*LSTR_ + (size_t)b*BSTR_;

  // clamped load rows
  int trow[4];
#pragma unroll
  for (int nt=0;nt<4;nt++){
    int t = t0 + nt*16 + ln;
    trow[nt] = (t < Tout) ? t : (Tout-1);
  }
  const unsigned short* __restrict__ xbB = xbin + (size_t)b*BSTR_;

  // ---- Phase B: in_act[256][64] = Wd0@x[t] + Wd1@x[t+d] + bd
  f32x4 acc[4][4];
#pragma unroll
  for (int mi=0;mi<4;mi++){
    int row = (mi<2) ? (w*32 + mi*16) : (128 + w*32 + (mi-2)*16);
    float4 bv = *(const float4*)(bd_l + row + q*4);
    f32x4 bi; bi[0]=bv.x; bi[1]=bv.y; bi[2]=bv.z; bi[3]=bv.w;
#pragma unroll
    for (int nt=0;nt<4;nt++) acc[mi][nt] = bi;
  }
#pragma unroll
  for (int tap=0;tap<2;tap++){
    const unsigned short* Wt = tap ? Wd1 : Wd0;
    int dd = tap ? d : 0;
#pragma unroll
    for (int ks=0;ks<4;ks++){
      bf16x8 bfr[4];
#pragma unroll
      for (int nt=0;nt<4;nt++)
        bfr[nt] = *(const bf16x8*)((const void*)(xbB + (size_t)(trow[nt]+dd)*128 + ks*32 + q*8));
      bf16x8 afr[4];
#pragma unroll
      for (int mi=0;mi<4;mi++){
        // row = (mi<2)? w*32+mi*16 : 128+w*32+(mi-2)*16  -> 16-row tile index:
        int mt = (mi<2) ? (w*2+mi) : (8 + w*2 + (mi-2));   // FIXED: 128>>4 == 8 (was 16: read next layer's weights)
        afr[mi] = *(const bf16x8*)((const void*)(Wt + (size_t)mt*2048 + ks*512 + (size_t)lane*8));
      }
#pragma unroll
      for (int mi=0;mi<4;mi++)
#pragma unroll
        for (int nt=0;nt<4;nt++)
          acc[mi][nt] = MFMA(afr[mi], bfr[nt], acc[mi][nt]);
    }
  }

  // ---- gate -> acts (global frag layout, K=128 rows t)
#pragma unroll
  for (int mi=0;mi<2;mi++)
#pragma unroll
    for (int nt=0;nt<4;nt++){
      f32x4 vt = acc[mi][nt], vs = acc[mi+2][nt];
      ushort4 pk;
      pk.x = f2bf(tanh_(vt[0])*sigm_(vs[0]));
      pk.y = f2bf(tanh_(vt[1])*sigm_(vs[1]));
      pk.z = f2bf(tanh_(vt[2])*sigm_(vs[2]));
      pk.w = f2bf(tanh_(vt[3])*sigm_(vs[3]));
      int tl = nt*16 + ln;
      int c0 = w*32 + mi*16 + q*4;
      if (tl < ntv)
        *(ushort4*)((void*)(actsF + fragAddr(t0+tl, c0, 128))) = pk;
    }
  __threadfence();
  __syncthreads();

  // ---- Phase C: res[128][64] = Wr@acts + br + x[t+d]
  f32x4 a2[2][4];
#pragma unroll
  for (int mi=0;mi<2;mi++){
    float4 bv = *(const float4*)(br_l + w*32 + mi*16 + q*4);
    f32x4 bi; bi[0]=bv.x; bi[1]=bv.y; bi[2]=bv.z; bi[3]=bv.w;
#pragma unroll
    for (int nt=0;nt<4;nt++) a2[mi][nt] = bi;
  }
#pragma unroll
  for (int ks=0;ks<4;ks++){
    bf16x8 bfr[4];
#pragma unroll
    for (int nt=0;nt<4;nt++)
      bfr[nt] = *(const bf16x8*)((const void*)(actsF + (size_t)((t0>>4)+nt)*2048 + ks*512 + (size_t)lane*8));
    bf16x8 afr[2];
#pragma unroll
    for (int mi=0;mi<2;mi++)
      afr[mi] = *(const bf16x8*)((const void*)(WrF + (size_t)(w*2+mi)*2048 + ks*512 + (size_t)lane*8));
#pragma unroll
    for (int mi=0;mi<2;mi++)
#pragma unroll
      for (int nt=0;nt<4;nt++)
        a2[mi][nt] = MFMA(afr[mi], bfr[nt], a2[mi][nt]);
  }
  // ---- epilogue: residual add (fp32) + bf16 mirror
#pragma unroll
  for (int mi=0;mi<2;mi++)
#pragma unroll
    for (int nt=0;nt<4;nt++){
      int tl = nt*16 + ln;
      if (tl < ntv){
        int c0 = w*32 + mi*16 + q*4;
        size_t xi = (size_t)b*T_ + t0 + tl;
        float4 xr = ((const float4*)xin)[(xi + d)*32 + (c0>>2)];
        f32x4 v = a2[mi][nt];
        float4 ov; ov.x=v[0]+xr.x; ov.y=v[1]+xr.y; ov.z=v[2]+xr.z; ov.w=v[3]+xr.w;
        ((float4*)xout)[xi*32 + (c0>>2)] = ov;
        ushort4 pb; pb.x=f2bf(ov.x); pb.y=f2bf(ov.y); pb.z=f2bf(ov.z); pb.w=f2bf(ov.w);
        *(ushort4*)((void*)(xbout + xi*128 + c0)) = pb;
      }
    }
}

// ---------------- frag-streaming GEMM, zero-LDS ----------------
// MODE 0: skip = WsF[512x2560] @ actsF + bssum, relu -> skipF
// MODE 1: h1   = W1F[512x512]  @ skipF,  relu -> h1F
// MODE 2: out  = W2F[256x512]  @ h1F -> fp32 out[b][o][t]
// 512 threads = 8 waves; block tile M_all x N=128; wave: m-frags MFR, n-frags 8.
template<int MODE>
__global__ __launch_bounds__(512,2) void gemm_frag(float* __restrict__ outF){
  constexpr int KTOT = (MODE==0)?2560:512;
  constexpr int MFR  = (MODE==2)?2:4;
  constexpr int NCH  = KTOT/64;
  const unsigned short* __restrict__ A = (MODE==0)?g_WsF:(MODE==1)?g_W1F:g_W2F;

  const int tid = threadIdx.x;
  const int w   = tid >> 6;
  const int lane= tid & 63;
  const int q   = lane >> 4;
  const int ln  = lane & 15;
  const int n0  = blockIdx.x*128;

  int tsn[8]; size_t bbase[8];   // MODE 0
  size_t rowoff[8];              // MODE 1/2
  int bArr[8], tsArr[8], nvalid[8];
#pragma unroll
  for (int nt=0;nt<8;nt++){
    int n = n0 + nt*16 + ln;
    nvalid[nt] = (n < NTOT_);
    if (n > NTOT_-1) n = NTOT_-1;
    int bb = (n >= 3*FOUT_) ? 3 : (n >= 2*FOUT_) ? 2 : (n >= FOUT_) ? 1 : 0;
    int ts = n - bb*FOUT_;
    bArr[nt]=bb; tsArr[nt]=ts;
    if (MODE==0){ tsn[nt]=ts; bbase[nt]=(size_t)bb*BSTR_; }
    else rowoff[nt] = (size_t)(n>>4)*8192 + (size_t)(n&15)*8;
  }

  f32x4 acc[MFR][8];
#pragma unroll
  for (int mi=0;mi<MFR;mi++)
#pragma unroll
    for (int nt=0;nt<8;nt++){ f32x4 z; z[0]=0;z[1]=0;z[2]=0;z[3]=0; acc[mi][nt]=z; }

  for (int ch=0; ch<NCH; ch++){
    const unsigned short* bptr[8];
    if (MODE==0){
      int l = ch >> 1;
      size_t base = (size_t)l*LSTR_ + (size_t)((ch&1)*2)*512;
#pragma unroll
      for (int nt=0;nt<8;nt++){
        int tv = tsn[nt] + d_OFF[l];
        bptr[nt] = g_actsF + base + bbase[nt] + (size_t)(tv>>4)*2048 + (size_t)(tv&15)*8;
      }
    } else {
      const unsigned short* BS = (MODE==1)?g_skipF:g_h1F;
#pragma unroll
      for (int nt=0;nt<8;nt++)
        bptr[nt] = BS + rowoff[nt] + (size_t)(ch*2)*512;
    }
#pragma unroll
    for (int kst=0;kst<2;kst++){
      bf16x8 bfr[8];
#pragma unroll
      for (int nt=0;nt<8;nt++)
        bfr[nt] = *(const bf16x8*)((const void*)(bptr[nt] + kst*512 + q*128));
      bf16x8 afr[MFR];
#pragma unroll
      for (int mi=0;mi<MFR;mi++){
        int mt = w*MFR + mi;
        afr[mi] = *(const bf16x8*)((const void*)(A + (size_t)mt*((KTOT>>5)*512)
                    + (size_t)(ch*2+kst)*512 + (size_t)lane*8));
      }
#pragma unroll
      for (int mi=0;mi<MFR;mi++)
#pragma unroll
        for (int nt=0;nt<8;nt++)
          acc[mi][nt] = MFMA(afr[mi], bfr[nt], acc[mi][nt]);
    }
  }

  // epilogue
#pragma unroll
  for (int mi=0;mi<MFR;mi++){
    int m = w*(MFR*16) + mi*16 + q*4;
    float4 bv;
    if (MODE==0) bv = *(const float4*)(g_bssum + m);
#pragma unroll
    for (int nt=0;nt<8;nt++){
      if (!nvalid[nt]) continue;
      int n = n0 + nt*16 + ln;
      f32x4 v = acc[mi][nt];
      if (MODE==0){ v[0]+=bv.x; v[1]+=bv.y; v[2]+=bv.z; v[3]+=bv.w; }
      if (MODE!=2){
        v[0]=fmaxf(v[0],0.f); v[1]=fmaxf(v[1],0.f);
        v[2]=fmaxf(v[2],0.f); v[3]=fmaxf(v[3],0.f);
        unsigned short* dst = (MODE==0)?g_skipF:g_h1F;
        // B-frag layout for next GEMM: rows n, k=m, K=512
        size_t a = (size_t)(n>>4)*8192 + (size_t)(m>>5)*512 + (size_t)((m>>3)&3)*128
                 + (size_t)(n&15)*8 + (size_t)(m&7);
        ushort4 pk; pk.x=f2bf(v[0]); pk.y=f2bf(v[1]); pk.z=f2bf(v[2]); pk.w=f2bf(v[3]);
        *(ushort4*)((void*)(dst + a)) = pk;
      } else {
        int bb = bArr[nt], ts = tsArr[nt];
#pragma unroll
        for (int r=0;r<4;r++)
          outF[((size_t)bb*256 + m + r)*FOUT_ + ts] = v[r];
      }
    }
  }
}

// ---------------- host launch ----------------
extern "C" void kernel_launch(void* const* d_in, const int* in_sizes, int n_in,
                              void* d_out, int out_size, void* d_ws, size_t ws_size,
                              hipStream_t stream) {
  const int*   y     = (const int*)  d_in[0];
  const float* embed = (const float*)d_in[1];
  const float* Wd    = (const float*)d_in[2];
  const float* bd    = (const float*)d_in[3];
  const float* Ws    = (const float*)d_in[4];
  const float* bs    = (const float*)d_in[5];
  const float* Wr    = (const float*)d_in[6];
  const float* br    = (const float*)d_in[7];
  const float* W1    = (const float*)d_in[8];
  const float* W2    = (const float*)d_in[9];
  float* out = (float*)d_out;
  (void)d_ws; (void)ws_size;

  cvt_wd<<<dim3((NL_*256*16+255)/256), dim3(256), 0, stream>>>(Wd);
  cvt_rm<<<dim3((2560*16+255)/256), dim3(256), 0, stream>>>(Wr, 0, 2560, 128);
  cvt_rm<<<dim3(( 512*64+255)/256), dim3(256), 0, stream>>>(W1, 1,  512, 512);
  cvt_rm<<<dim3(( 256*64+255)/256), dim3(256), 0, stream>>>(W2, 2,  256, 512);
  cvt_ws<<<dim3((NL_*512*16+255)/256), dim3(256), 0, stream>>>(Ws);
  bssum_k<<<dim3(1), dim3(512), 0, stream>>>(bs);

  embed_kernel<<<dim3((B_*T_*32)/256), dim3(256), 0, stream>>>(y, embed);

  static const int DIL[NL_] = {1,2,4,8,16,32,64,128,256,512,
                               1,2,4,8,16,32,64,128,256,512};
  int swap = 0;
  int Tin = T_;
  for (int i=0;i<NL_;i++){
    int d = DIL[i];
    int Tout = Tin - d;
    dim3 grid((Tout+63)/64, B_);
    layer_frag<<<grid, dim3(256), 0, stream>>>(
        swap, i, d, Tout, bd + (size_t)i*256, br + (size_t)i*128);
    swap ^= 1;
    Tin = Tout;
  }

  dim3 gg((NTOT_+127)/128);
  gemm_frag<0><<<gg, dim3(512), 0, stream>>>(nullptr);
  gemm_frag<1><<<gg, dim3(512), 0, stream>>>(nullptr);
  gemm_frag<2><<<gg, dim3(512), 0, stream>>>(out);
}

// Round 6
// 1182.932 us; speedup vs baseline: 3.1031x; 3.1031x over previous
//
#include <hip/hip_runtime.h>
#include <cstddef>

#define B_    4
#define T_    16384
#define WD_   128
#define SD_   512
#define FOUT_ 14337
#define NL_   20
#define NTOT_ (B_*FOUT_)                 // 57348
#define XB_STR   ((size_t)T_*128)        // per-b row stride (elements)
#define ACT_LSTR ((size_t)B_*T_*128)     // per-l stride of acts (shorts)

typedef float f32x16 __attribute__((ext_vector_type(16)));
typedef short bf16x8 __attribute__((ext_vector_type(8)));

// ---- static device buffers ----
__device__ float g_x0[(size_t)B_*T_*128];
__device__ float g_x1[(size_t)B_*T_*128];
__device__ unsigned short g_xB0[(size_t)B_*T_*128];
__device__ unsigned short g_xB1[(size_t)B_*T_*128];
__device__ unsigned short g_WdF0[(size_t)NL_*256*128];  // frag layout, K=128 (tap0)
__device__ unsigned short g_WdF1[(size_t)NL_*256*128];  // tap1
__device__ unsigned short g_WrF [(size_t)NL_*128*128];
__device__ unsigned short g_WsF [(size_t)512*2560];
__device__ unsigned short g_W1F [(size_t)512*512];
__device__ unsigned short g_W2F [(size_t)256*512];
__device__ float g_bssum[512];
__device__ unsigned short g_acts[(size_t)NL_*B_*T_*128]; // [l][b][t][128] bf16 rows
__device__ unsigned short g_skipB[(size_t)NTOT_*512];    // relu(skip) [n][512]
__device__ unsigned short g_h1B [(size_t)NTOT_*512];     // relu(h1)   [n][512]

__constant__ int d_OFF[NL_] = {2046,2044,2040,2032,2016,1984,1920,1792,1536,1024,
                               1023,1021,1017,1009, 993, 961, 897, 769, 513,   1};

__device__ __forceinline__ unsigned short f2bf(float f){
  unsigned u = __float_as_uint(f);
  u += 0x7FFF + ((u >> 16) & 1u);
  return (unsigned short)(u >> 16);
}
__device__ __forceinline__ float sigm_(float x){ return 1.0f/(1.0f+__expf(-x)); }
__device__ __forceinline__ float tanh_(float x){ return 1.0f - 2.0f/(__expf(2.0f*x)+1.0f); }
__device__ __forceinline__ f32x16 MFMA32(bf16x8 a, bf16x8 b, f32x16 c){
  return __builtin_amdgcn_mfma_f32_32x32x16_bf16(a, b, c, 0, 0, 0);
}
// A/B fragment global layout: per 32-row tile, per 16-k step: 1KB block = lane*16B,
// element (row,k): lane = ((k&15)>>3)*32 + (row&31), j = k&7.

// ---------------- weight conversion ----------------
__global__ void cvt_wd(const float* __restrict__ Wd){
  int i = blockIdx.x*256 + threadIdx.x;
  if (i >= NL_*256*16) return;
  int row = i >> 4, koct = i & 15;            // row = l*256+m, k0 = koct*8
  const float* s = Wd + ((size_t)row*128 + koct*8)*2;
  int lane = (koct&1)*32 + (row&31);
  size_t addr = (size_t)((row>>5)*8 + (koct>>1))*512 + lane*8;
  unsigned short u0[8], u1[8];
#pragma unroll
  for (int j=0;j<8;j++){ u0[j]=f2bf(s[2*j]); u1[j]=f2bf(s[2*j+1]); }
  *(uint4*)((void*)(g_WdF0 + addr)) = *(const uint4*)((const void*)u0);
  *(uint4*)((void*)(g_WdF1 + addr)) = *(const uint4*)((const void*)u1);
}
// row-major [M][K] fp32 -> frag bf16. which: 0=Wr(2560x128) 1=W1(512x512) 2=W2(256x512)
__global__ void cvt_rm(const float* __restrict__ src, int which, int M, int K){
  int i = blockIdx.x*256 + threadIdx.x;
  if (i >= M*(K>>3)) return;
  int row = i / (K>>3), koct = i % (K>>3);
  const float* s = src + (size_t)row*K + koct*8;
  int lane = (koct&1)*32 + (row&31);
  size_t addr = ((size_t)(row>>5)*(K>>4) + (koct>>1))*512 + lane*8;
  unsigned short u[8];
#pragma unroll
  for (int j=0;j<8;j++) u[j]=f2bf(s[j]);
  unsigned short* dst = (which==0)?g_WrF:(which==1)?g_W1F:g_W2F;
  *(uint4*)((void*)(dst + addr)) = *(const uint4*)((const void*)u);
}
// Ws [L][512][128] -> frag rows o, K=2560 (k=l*128+c)
__global__ void cvt_ws(const float* __restrict__ Ws){
  int i = blockIdx.x*256 + threadIdx.x;
  if (i >= NL_*512*16) return;
  int l = i >> 13, o = (i>>4)&511, coct = i&15;
  const float* s = Ws + ((size_t)(l*512+o))*128 + coct*8;
  int lane = (coct&1)*32 + (o&31);
  size_t addr = ((size_t)(o>>5)*160 + (size_t)(l*8 + (coct>>1)))*512 + lane*8;
  unsigned short u[8];
#pragma unroll
  for (int j=0;j<8;j++) u[j]=f2bf(s[j]);
  *(uint4*)((void*)(g_WsF + addr)) = *(const uint4*)((const void*)u);
}
__global__ void bssum_k(const float* __restrict__ bs){
  int o = threadIdx.x;
  float s = 0.f;
  for (int l=0;l<NL_;l++) s += bs[l*512 + o];
  g_bssum[o] = s;
}

// ---------------- embedding ----------------
__global__ void embed_kernel(const int* __restrict__ y, const float* __restrict__ embed){
  int gid = blockIdx.x*256 + threadIdx.x;
  int bt  = gid >> 5, c4 = gid & 31;
  if (bt < B_*T_){
    int idx = y[bt];
    float4 v = ((const float4*)embed)[(size_t)idx*32 + c4];
    ((float4*)g_x0)[(size_t)bt*32 + c4] = v;
    ushort4 p; p.x=f2bf(v.x); p.y=f2bf(v.y); p.z=f2bf(v.z); p.w=f2bf(v.w);
    *(ushort4*)((void*)(g_xB0 + (size_t)bt*128 + c4*4)) = p;
  }
}

// ---------------- fused layer: 32x32x16 MFMA, LDS chunk-transposed B ----------------
// 256 threads = 4 waves. Block tile: 64 t x 256 in_act rows.
// LDS tile layout: chunk c16 = c>>3 (16 chunks), addr_sh = c16*520 + t*8 + (c&7).
__global__ __launch_bounds__(256,3) void layer32(
    int swap, int l, int d, int Tout,
    const float* __restrict__ bd_l, const float* __restrict__ br_l)
{
  const float* __restrict__ xin  = swap ? g_x1 : g_x0;
  float* __restrict__       xout = swap ? g_x0 : g_x1;
  const unsigned short* __restrict__ xbin  = swap ? g_xB1 : g_xB0;
  unsigned short* __restrict__       xbout = swap ? g_xB0 : g_xB1;

  __shared__ unsigned short X0[16*520];   // x[t0..t0+63]
  __shared__ unsigned short X1[16*520];   // x[t0+d..]
  __shared__ unsigned short AC[16*520];   // acts tile

  const int tid = threadIdx.x;
  const int w   = tid >> 6;
  const int lane= tid & 63;
  const int ln2 = lane & 31;
  const int h   = lane >> 5;
  const int b   = blockIdx.y;
  const int t0  = blockIdx.x*64;
  const int ntv = min(64, Tout - t0);
  const int limit = Tout + d - 1;        // = Tin-1
  const unsigned short* __restrict__ xbB = xbin + (size_t)b*XB_STR;

  // ---- stage both x tiles (coalesced global, 2-way-free LDS writes)
#pragma unroll
  for (int it=0; it<4; it++){
    int t = (tid>>4) + it*16, c16 = tid&15;
    int s0 = t0 + t;     if (s0 > limit) s0 = limit;
    int s1 = t0 + t + d; if (s1 > limit) s1 = limit;
    *(uint4*)((void*)&X0[c16*520 + t*8]) = *(const uint4*)((const void*)(xbB + (size_t)s0*128 + c16*8));
    *(uint4*)((void*)&X1[c16*520 + t*8]) = *(const uint4*)((const void*)(xbB + (size_t)s1*128 + c16*8));
  }
  __syncthreads();

  // ---- Phase B: in_act[256][64]; wave w: m-tiles {w (tanh), 4+w (sigm)}
  f32x16 aB[2][2];
#pragma unroll
  for (int mi=0;mi<2;mi++)
#pragma unroll
    for (int nt=0;nt<2;nt++)
#pragma unroll
      for (int r=0;r<16;r++) aB[mi][nt][r] = 0.f;

#pragma unroll
  for (int tap=0; tap<2; tap++){
    const unsigned short* __restrict__ Xs = tap ? X1 : X0;
    const unsigned short* __restrict__ Wt = (tap ? g_WdF1 : g_WdF0) + (size_t)l*32768;
    const unsigned short* aT = Wt + (size_t)(w  )*4096 + lane*8;
    const unsigned short* aS = Wt + (size_t)(4+w)*4096 + lane*8;
#pragma unroll
    for (int ks=0; ks<8; ks++){
      bf16x8 bfr[2];
#pragma unroll
      for (int nt=0; nt<2; nt++)
        bfr[nt] = *(const bf16x8*)((const void*)&Xs[(ks*2+h)*520 + (nt*32+ln2)*8]);
      bf16x8 fT = *(const bf16x8*)((const void*)(aT + ks*512));
      bf16x8 fS = *(const bf16x8*)((const void*)(aS + ks*512));
#pragma unroll
      for (int nt=0; nt<2; nt++){
        aB[0][nt] = MFMA32(fT, bfr[nt], aB[0][nt]);
        aB[1][nt] = MFMA32(fS, bfr[nt], aB[1][nt]);
      }
    }
  }

  // ---- gate -> acts LDS (C layout: col=ln2, row=(r&3)+8*(r>>2)+4h)
#pragma unroll
  for (int nt=0; nt<2; nt++)
#pragma unroll
    for (int rq=0; rq<4; rq++){
      int c0 = w*32 + rq*8 + 4*h;
      const float* bT = bd_l + c0;
      const float* bS = bd_l + 128 + c0;
      ushort4 pk; unsigned short* pp = (unsigned short*)&pk;
#pragma unroll
      for (int rr=0; rr<4; rr++){
        float it_ = aB[0][nt][rq*4+rr] + bT[rr];
        float is_ = aB[1][nt][rq*4+rr] + bS[rr];
        pp[rr] = f2bf(tanh_(it_)*sigm_(is_));
      }
      *(ushort4*)((void*)&AC[(w*4+rq)*520 + (nt*32+ln2)*8 + 4*h]) = pk;
    }
  __syncthreads();

  // ---- Phase C: res[128][64] = Wr@acts; wave w: m-tile w
  f32x16 aC[2];
#pragma unroll
  for (int nt=0;nt<2;nt++)
#pragma unroll
    for (int r=0;r<16;r++) aC[nt][r] = 0.f;
  {
    const unsigned short* aW = g_WrF + (size_t)l*16384 + (size_t)w*4096 + lane*8;
#pragma unroll
    for (int ks=0; ks<8; ks++){
      bf16x8 bfr[2];
#pragma unroll
      for (int nt=0; nt<2; nt++)
        bfr[nt] = *(const bf16x8*)((const void*)&AC[(ks*2+h)*520 + (nt*32+ln2)*8]);
      bf16x8 fW = *(const bf16x8*)((const void*)(aW + ks*512));
#pragma unroll
      for (int nt=0; nt<2; nt++)
        aC[nt] = MFMA32(fW, bfr[nt], aC[nt]);
    }
  }

  // ---- epilogue: x_new = res + br + x_fp32[t+d]; write fp32 + bf16 mirror
#pragma unroll
  for (int nt=0; nt<2; nt++){
    int t = nt*32 + ln2;
    if (t < ntv){
      size_t xi = (size_t)b*T_ + t0 + t;
#pragma unroll
      for (int rq=0; rq<4; rq++){
        int c0 = w*32 + rq*8 + 4*h;
        const float* xp = xin + (xi + d)*128 + c0;
        const float* bp = br_l + c0;
        float ov[4];
#pragma unroll
        for (int rr=0; rr<4; rr++) ov[rr] = aC[nt][rq*4+rr] + bp[rr] + xp[rr];
        *(float4*)((void*)(xout + xi*128 + c0)) = *(const float4*)((const void*)ov);
        ushort4 pm; pm.x=f2bf(ov[0]); pm.y=f2bf(ov[1]); pm.z=f2bf(ov[2]); pm.w=f2bf(ov[3]);
        *(ushort4*)((void*)(xbout + xi*128 + c0)) = pm;
      }
    }
  }

  // ---- acts LDS -> global (linear, coalesced), rows t0..t0+63
  unsigned short* __restrict__ actsG = g_acts + (size_t)l*ACT_LSTR + (size_t)b*XB_STR;
#pragma unroll
  for (int it=0; it<4; it++){
    int t = (tid>>4) + it*16, c16 = tid&15;
    *(uint4*)((void*)(actsG + (size_t)(t0+t)*128 + c16*8)) =
        *(const uint4*)((const void*)&AC[c16*520 + t*8]);
  }
}

// ---------------- big GEMMs: A from global frag, B via dbuf LDS ----------------
// MODE 0: skip = Ws[512x2560] @ acts + bssum, relu -> g_skipB
// MODE 1: h1   = W1[512x512]  @ skipB,  relu -> g_h1B
// MODE 2: out  = W2[256x512]  @ h1B -> fp32 out
// 512 threads = 8 waves; block: n-tile 128, all M; wave m-frags MFR, n-frags 4.
template<int MODE>
__global__ __launch_bounds__(512,2) void gemm_big(float* __restrict__ outF){
  constexpr int KTOT = (MODE==0)?2560:512;
  constexpr int MFR  = (MODE==2)?1:2;
  constexpr int NCH  = KTOT/128;
  const unsigned short* __restrict__ A = (MODE==0)?g_WsF:(MODE==1)?g_W1F:g_W2F;

  __shared__ unsigned short buf[2][16*1032];

  const int tid = threadIdx.x;
  const int w   = tid >> 6;
  const int lane= tid & 63;
  const int ln2 = lane & 31;
  const int h   = lane >> 5;
  const int n0  = blockIdx.x*128;

  // staging slot coords (4 x uint4 per thread per chunk)
  size_t sbase[4]; int dstsh[4];
#pragma unroll
  for (int it=0; it<4; it++){
    int nn = (tid>>4) + it*32, c16 = tid&15;
    int n = n0 + nn; if (n > NTOT_-1) n = NTOT_-1;
    if (MODE==0){
      int bb = (n >= 3*FOUT_) ? 3 : (n >= 2*FOUT_) ? 2 : (n >= FOUT_) ? 1 : 0;
      int ts = n - bb*FOUT_;
      sbase[it] = ((size_t)bb*T_ + ts)*128 + c16*8;
    } else {
      sbase[it] = (size_t)n*512 + c16*8;
    }
    dstsh[it] = c16*1032 + nn*8;
  }
  const unsigned short* __restrict__ Bsrc = (MODE==1)?g_skipB:g_h1B;

  f32x16 acc[MFR][4];
#pragma unroll
  for (int mi=0;mi<MFR;mi++)
#pragma unroll
    for (int nt=0;nt<4;nt++)
#pragma unroll
      for (int r=0;r<16;r++) acc[mi][nt][r] = 0.f;

  const unsigned short* Abase[MFR];
#pragma unroll
  for (int mi=0;mi<MFR;mi++)
    Abase[mi] = A + (size_t)(w*MFR+mi)*((KTOT>>4)*512) + lane*8;

  // prologue: stage chunk 0
  uint4 pf[4];
#pragma unroll
  for (int it=0; it<4; it++){
    const unsigned short* s = (MODE==0)
      ? (g_acts + (size_t)0*ACT_LSTR + (size_t)d_OFF[0]*128 + sbase[it])
      : (Bsrc + sbase[it]);
    pf[it] = *(const uint4*)((const void*)s);
  }
#pragma unroll
  for (int it=0; it<4; it++) *(uint4*)((void*)&buf[0][dstsh[it]]) = pf[it];

  for (int ch=0; ch<NCH; ch++){
    __syncthreads();
    if (ch+1 < NCH){
#pragma unroll
      for (int it=0; it<4; it++){
        const unsigned short* s = (MODE==0)
          ? (g_acts + (size_t)(ch+1)*ACT_LSTR + (size_t)d_OFF[ch+1]*128 + sbase[it])
          : (Bsrc + sbase[it] + (size_t)(ch+1)*128);
        pf[it] = *(const uint4*)((const void*)s);
      }
    }
    const unsigned short* __restrict__ cur = &buf[ch&1][0];
#pragma unroll
    for (int ks=0; ks<8; ks++){
      bf16x8 bfr[4];
#pragma unroll
      for (int nt=0; nt<4; nt++)
        bfr[nt] = *(const bf16x8*)((const void*)&cur[(ks*2+h)*1032 + (nt*32+ln2)*8]);
#pragma unroll
      for (int mi=0; mi<MFR; mi++){
        bf16x8 afr = *(const bf16x8*)((const void*)(Abase[mi] + (size_t)(ch*8+ks)*512));
#pragma unroll
        for (int nt=0; nt<4; nt++)
          acc[mi][nt] = MFMA32(afr, bfr[nt], acc[mi][nt]);
      }
    }
    if (ch+1 < NCH){
#pragma unroll
      for (int it=0; it<4; it++) *(uint4*)((void*)&buf[(ch+1)&1][dstsh[it]]) = pf[it];
    }
  }

  // epilogue
#pragma unroll
  for (int mi=0; mi<MFR; mi++)
#pragma unroll
    for (int nt=0; nt<4; nt++){
      int n = n0 + nt*32 + ln2;
      if (n >= NTOT_) continue;
#pragma unroll
      for (int rq=0; rq<4; rq++){
        int c0 = (w*MFR+mi)*32 + rq*8 + 4*h;
        float v[4];
#pragma unroll
        for (int rr=0; rr<4; rr++) v[rr] = acc[mi][nt][rq*4+rr];
        if (MODE==0){
          const float* bp = g_bssum + c0;
#pragma unroll
          for (int rr=0; rr<4; rr++) v[rr] += bp[rr];
        }
        if (MODE!=2){
#pragma unroll
          for (int rr=0; rr<4; rr++) v[rr] = fmaxf(v[rr], 0.f);
          unsigned short* dst = (MODE==0)?g_skipB:g_h1B;
          ushort4 pk; pk.x=f2bf(v[0]); pk.y=f2bf(v[1]); pk.z=f2bf(v[2]); pk.w=f2bf(v[3]);
          *(ushort4*)((void*)(dst + (size_t)n*512 + c0)) = pk;
        } else {
          int bb = (n >= 3*FOUT_) ? 3 : (n >= 2*FOUT_) ? 2 : (n >= FOUT_) ? 1 : 0;
          int ts = n - bb*FOUT_;
#pragma unroll
          for (int rr=0; rr<4; rr++)
            outF[((size_t)(bb*256 + c0 + rr))*FOUT_ + ts] = v[rr];
        }
      }
    }
}

// ---------------- host launch ----------------
extern "C" void kernel_launch(void* const* d_in, const int* in_sizes, int n_in,
                              void* d_out, int out_size, void* d_ws, size_t ws_size,
                              hipStream_t stream) {
  const int*   y     = (const int*)  d_in[0];
  const float* embed = (const float*)d_in[1];
  const float* Wd    = (const float*)d_in[2];
  const float* bd    = (const float*)d_in[3];
  const float* Ws    = (const float*)d_in[4];
  const float* bs    = (const float*)d_in[5];
  const float* Wr    = (const float*)d_in[6];
  const float* br    = (const float*)d_in[7];
  const float* W1    = (const float*)d_in[8];
  const float* W2    = (const float*)d_in[9];
  float* out = (float*)d_out;
  (void)d_ws; (void)ws_size;

  cvt_wd<<<dim3(320), dim3(256), 0, stream>>>(Wd);
  cvt_rm<<<dim3(160), dim3(256), 0, stream>>>(Wr, 0, NL_*128, 128);
  cvt_rm<<<dim3(128), dim3(256), 0, stream>>>(W1, 1, 512, 512);
  cvt_rm<<<dim3( 64), dim3(256), 0, stream>>>(W2, 2, 256, 512);
  cvt_ws<<<dim3(640), dim3(256), 0, stream>>>(Ws);
  bssum_k<<<dim3(1), dim3(512), 0, stream>>>(bs);

  embed_kernel<<<dim3((B_*T_*32)/256), dim3(256), 0, stream>>>(y, embed);

  static const int DIL[NL_] = {1,2,4,8,16,32,64,128,256,512,
                               1,2,4,8,16,32,64,128,256,512};
  int swap = 0;
  int Tin = T_;
  for (int i=0;i<NL_;i++){
    int d = DIL[i];
    int Tout = Tin - d;
    dim3 grid((Tout+63)/64, B_);
    layer32<<<grid, dim3(256), 0, stream>>>(
        swap, i, d, Tout, bd + (size_t)i*256, br + (size_t)i*128);
    swap ^= 1;
    Tin = Tout;
  }

  dim3 gg((NTOT_+127)/128);
  gemm_big<0><<<gg, dim3(512), 0, stream>>>(nullptr);
  gemm_big<1><<<gg, dim3(512), 0, stream>>>(nullptr);
  gemm_big<2><<<gg, dim3(512), 0, stream>>>(out);
}

// Round 7
// 1063.242 us; speedup vs baseline: 3.4524x; 1.1126x over previous
//
#include <hip/hip_runtime.h>
#include <cstddef>

#define B_    4
#define T_    16384
#define FOUT_ 14337
#define FOUTP 14464                       // 113*128, frag-tile padded
#define NL_   20
#define XSTR  ((size_t)T_*128)            // x per-b stride (halfs)
#define ABSTR ((size_t)FOUTP*128)         // acts per-b stride (halfs)
#define ALSTR ((size_t)B_*FOUTP*128)      // acts per-l stride
#define SBSTR ((size_t)FOUTP*512)         // skip/h1 per-b stride

typedef float    f32x16 __attribute__((ext_vector_type(16)));
typedef _Float16 f16x8  __attribute__((ext_vector_type(8)));

// ---- static device buffers (zero-init at load; pad regions never written) ----
__device__ _Float16 g_xh0[(size_t)B_*T_*128];
__device__ _Float16 g_xh1[(size_t)B_*T_*128];
__device__ _Float16 g_WdF0[(size_t)NL_*256*128];   // frag layout, K=128, tap0
__device__ _Float16 g_WdF1[(size_t)NL_*256*128];   // tap1
__device__ _Float16 g_WrF [(size_t)NL_*128*128];
__device__ _Float16 g_WsF [(size_t)512*2560];
__device__ _Float16 g_W1F [(size_t)512*512];
__device__ _Float16 g_W2F [(size_t)256*512];
__device__ float    g_bssum[512];
__device__ _Float16 g_acts[(size_t)NL_*B_*FOUTP*128];  // B-frag layout per (l,b), rows ts, K=128
__device__ _Float16 g_skipF[(size_t)B_*FOUTP*512];     // B-frag layout, rows ts, K=512
__device__ _Float16 g_h1F [(size_t)B_*FOUTP*512];

__device__ __forceinline__ float sigm_(float x){ return 1.0f/(1.0f+__expf(-x)); }
__device__ __forceinline__ float tanh_(float x){ return 1.0f - 2.0f/(__expf(2.0f*x)+1.0f); }
__device__ __forceinline__ f32x16 MFMA32(f16x8 a, f16x8 b, f32x16 c){
  return __builtin_amdgcn_mfma_f32_32x32x16_f16(a, b, c, 0, 0, 0);
}
// Fragment layout (A rows=m / B rows=n): per 32-row tile, per k-step(16):
// 1KB block, element(row,k): lane = ((k>>3)&1)*32 + (row&31), j = k&7.

// ---------------- weight conversion ----------------
__global__ void cvt_wd(const float* __restrict__ Wd){
  int i = blockIdx.x*256 + threadIdx.x;
  if (i >= NL_*256*16) return;
  int row = i >> 4, koct = i & 15;
  const float* s = Wd + ((size_t)row*128 + koct*8)*2;
  int lane = (koct&1)*32 + (row&31);
  size_t addr = (size_t)((row>>5)*8 + (koct>>1))*512 + lane*8;
  union { _Float16 h[8]; uint4 v; } u0, u1;
#pragma unroll
  for (int j=0;j<8;j++){ u0.h[j]=(_Float16)s[2*j]; u1.h[j]=(_Float16)s[2*j+1]; }
  *(uint4*)((void*)(g_WdF0 + addr)) = u0.v;
  *(uint4*)((void*)(g_WdF1 + addr)) = u1.v;
}
__global__ void cvt_rm(const float* __restrict__ src, int which, int M, int K){
  int i = blockIdx.x*256 + threadIdx.x;
  if (i >= M*(K>>3)) return;
  int row = i / (K>>3), koct = i % (K>>3);
  const float* s = src + (size_t)row*K + koct*8;
  int lane = (koct&1)*32 + (row&31);
  size_t addr = ((size_t)(row>>5)*(K>>4) + (koct>>1))*512 + lane*8;
  union { _Float16 h[8]; uint4 v; } u;
#pragma unroll
  for (int j=0;j<8;j++) u.h[j]=(_Float16)s[j];
  _Float16* dst = (which==0)?g_WrF:(which==1)?g_W1F:g_W2F;
  *(uint4*)((void*)(dst + addr)) = u.v;
}
__global__ void cvt_ws(const float* __restrict__ Ws){
  int i = blockIdx.x*256 + threadIdx.x;
  if (i >= NL_*512*16) return;
  int l = i >> 13, o = (i>>4)&511, coct = i&15;
  const float* s = Ws + ((size_t)(l*512+o))*128 + coct*8;
  int lane = (coct&1)*32 + (o&31);
  size_t addr = ((size_t)(o>>5)*160 + (size_t)(l*8 + (coct>>1)))*512 + lane*8;
  union { _Float16 h[8]; uint4 v; } u;
#pragma unroll
  for (int j=0;j<8;j++) u.h[j]=(_Float16)s[j];
  *(uint4*)((void*)(g_WsF + addr)) = u.v;
}
__global__ void bssum_k(const float* __restrict__ bs){
  int o = threadIdx.x;
  float s = 0.f;
  for (int l=0;l<NL_;l++) s += bs[l*512 + o];
  g_bssum[o] = s;
}

// ---------------- embedding -> fp16 x0 ----------------
__global__ void embed_kernel(const int* __restrict__ y, const float* __restrict__ embed){
  int gid = blockIdx.x*256 + threadIdx.x;
  int bt = gid >> 4, c8 = gid & 15;
  if (bt < B_*T_){
    int idx = y[bt];
    const float* e = embed + (size_t)idx*128 + c8*8;
    union { _Float16 h[8]; uint4 v; } u;
#pragma unroll
    for (int j=0;j<8;j++) u.h[j]=(_Float16)e[j];
    *(uint4*)((void*)(g_xh0 + (size_t)bt*128 + c8*8)) = u.v;
  }
}

// ---------------- fused layer: fp16, 32x32x16 MFMA, frag acts output ----------------
// 256 threads = 4 waves; block tile 64 t x full channels.
// LDS tile: octet c16 = c>>3, addr = c16*520 + t*8 + (c&7).
__global__ __launch_bounds__(256,3) void layer16(
    int swap, int l, int d, int Tout, int ss,
    const float* __restrict__ bd_l, const float* __restrict__ br_l)
{
  const _Float16* __restrict__ xin  = swap ? g_xh1 : g_xh0;
  _Float16* __restrict__       xout = swap ? g_xh0 : g_xh1;

  __shared__ _Float16 X0s[16*520];
  __shared__ _Float16 X1s[16*520];
  __shared__ _Float16 ACs[16*520];

  const int tid = threadIdx.x;
  const int w   = tid >> 6;
  const int lane= tid & 63;
  const int ln2 = lane & 31;
  const int h   = lane >> 5;
  const int b   = blockIdx.y;
  const int t0  = blockIdx.x*64;
  const int ntv = min(64, Tout - t0);
  const int limit = Tout + d - 1;
  const _Float16* __restrict__ xb = xin + (size_t)b*XSTR;

  // ---- stage both taps
#pragma unroll
  for (int it=0; it<4; it++){
    int t = (tid>>4) + it*16, c16 = tid&15;
    int s0 = t0 + t;     if (s0 > limit) s0 = limit;
    int s1 = t0 + t + d; if (s1 > limit) s1 = limit;
    *(uint4*)((void*)&X0s[c16*520 + t*8]) = *(const uint4*)((const void*)(xb + (size_t)s0*128 + c16*8));
    *(uint4*)((void*)&X1s[c16*520 + t*8]) = *(const uint4*)((const void*)(xb + (size_t)s1*128 + c16*8));
  }
  __syncthreads();

  // ---- Phase B: in_act[256][64]; wave w: m-tiles {w (tanh), 4+w (sigm)}
  f32x16 aB[2][2];
#pragma unroll
  for (int mi=0;mi<2;mi++)
#pragma unroll
    for (int nt=0;nt<2;nt++)
#pragma unroll
      for (int r=0;r<16;r++) aB[mi][nt][r] = 0.f;

#pragma unroll
  for (int tap=0; tap<2; tap++){
    const _Float16* __restrict__ Xs = tap ? X1s : X0s;
    const _Float16* __restrict__ Wt = (tap ? g_WdF1 : g_WdF0) + (size_t)l*32768;
    const _Float16* aT = Wt + (size_t)w*4096 + lane*8;
    const _Float16* aS = Wt + (size_t)(4+w)*4096 + lane*8;
#pragma unroll
    for (int ks=0; ks<8; ks++){
      f16x8 bfr[2];
#pragma unroll
      for (int nt=0; nt<2; nt++)
        bfr[nt] = *(const f16x8*)((const void*)&Xs[(ks*2+h)*520 + (nt*32+ln2)*8]);
      f16x8 fT = *(const f16x8*)((const void*)(aT + ks*512));
      f16x8 fS = *(const f16x8*)((const void*)(aS + ks*512));
#pragma unroll
      for (int nt=0; nt<2; nt++){
        aB[0][nt] = MFMA32(fT, bfr[nt], aB[0][nt]);
        aB[1][nt] = MFMA32(fS, bfr[nt], aB[1][nt]);
      }
    }
  }

  // ---- gate -> ACs
#pragma unroll
  for (int nt=0; nt<2; nt++)
#pragma unroll
    for (int rq=0; rq<4; rq++){
      int c0 = w*32 + rq*8 + 4*h;
      union { _Float16 hh[4]; ushort4 v; } pk;
#pragma unroll
      for (int rr=0; rr<4; rr++){
        float it_ = aB[0][nt][rq*4+rr] + bd_l[c0+rr];
        float is_ = aB[1][nt][rq*4+rr] + bd_l[128+c0+rr];
        pk.hh[rr] = (_Float16)(tanh_(it_)*sigm_(is_));
      }
      *(ushort4*)((void*)&ACs[(w*4+rq)*520 + (nt*32+ln2)*8 + 4*h]) = pk.v;
    }
  __syncthreads();

  // ---- Phase C: res[128][64] = Wr@acts
  f32x16 aC[2];
#pragma unroll
  for (int nt=0;nt<2;nt++)
#pragma unroll
    for (int r=0;r<16;r++) aC[nt][r] = 0.f;
  {
    const _Float16* aW = g_WrF + (size_t)l*16384 + (size_t)w*4096 + lane*8;
#pragma unroll
    for (int ks=0; ks<8; ks++){
      f16x8 bfr[2];
#pragma unroll
      for (int nt=0; nt<2; nt++)
        bfr[nt] = *(const f16x8*)((const void*)&ACs[(ks*2+h)*520 + (nt*32+ln2)*8]);
      f16x8 fW = *(const f16x8*)((const void*)(aW + ks*512));
#pragma unroll
      for (int nt=0; nt<2; nt++)
        aC[nt] = MFMA32(fW, bfr[nt], aC[nt]);
    }
  }

  // ---- epilogue: x_new = res + br + x[t+d] (x[t+d] from X1s), store fp16
#pragma unroll
  for (int nt=0; nt<2; nt++){
    int t = nt*32 + ln2;
    if (t < ntv){
      size_t xrow = (size_t)b*XSTR + (size_t)(t0+t)*128;
#pragma unroll
      for (int rq=0; rq<4; rq++){
        int c0 = w*32 + rq*8 + 4*h;
        union { ushort4 v; _Float16 hh[4]; } xr;
        xr.v = *(const ushort4*)((const void*)&X1s[(w*4+rq)*520 + t*8 + 4*h]);
        union { _Float16 hh[4]; ushort4 v; } ov;
#pragma unroll
        for (int rr=0; rr<4; rr++)
          ov.hh[rr] = (_Float16)(aC[nt][rq*4+rr] + br_l[c0+rr] + (float)xr.hh[rr]);
        *(ushort4*)((void*)(xout + xrow + c0)) = ov.v;
      }
    }
  }

  // ---- acts -> global B-frag layout indexed by ts
  _Float16* __restrict__ actsB = g_acts + (size_t)l*ALSTR + (size_t)b*ABSTR;
#pragma unroll
  for (int it=0; it<4; it++){
    int t = (tid>>4) + it*16, c16 = tid&15;
    int ts = t0 + t - ss;
    if (t < ntv && ts >= 0 && ts < FOUT_){
      size_t addr = (size_t)(ts>>5)*4096 + (size_t)(c16>>1)*512 + ((c16&1)*32 + (ts&31))*8;
      *(uint4*)((void*)(actsB + addr)) = *(const uint4*)((const void*)&ACs[c16*520 + t*8]);
    }
  }
}

// ---------------- streaming GEMMs: zero LDS, register-pipelined ----------------
// MODE 0: skip = Ws[512x2560] @ acts + bssum, relu -> g_skipF (frag)
// MODE 1: h1   = W1[512x512]  @ skipF, relu -> g_h1F (frag)
// MODE 2: out  = W2[256x512]  @ h1F -> fp32 out
// 512 threads = 8 waves; block: n-tile 128 (4 frag tiles), all M; grid (113, B).
template<int MODE>
__global__ __launch_bounds__(512,2) void gemm_stream(float* __restrict__ outF){
  constexpr int NSTEP = (MODE==0)?160:32;
  constexpr int MFR   = (MODE==2)?1:2;
  const _Float16* __restrict__ A    = (MODE==0)?g_WsF:(MODE==1)?g_W1F:g_W2F;
  const _Float16* __restrict__ Bsrc = (MODE==0)?g_acts:(MODE==1)?g_skipF:g_h1F;

  const int tid = threadIdx.x;
  const int w   = tid >> 6;
  const int lane= tid & 63;
  const int ln2 = lane & 31;
  const int h   = lane >> 5;
  const int b   = blockIdx.y;
  const int ts0 = blockIdx.x*128;

  const _Float16* Bb[4];
#pragma unroll
  for (int nt=0;nt<4;nt++){
    size_t tile = blockIdx.x*4 + nt;
    Bb[nt] = (MODE==0) ? (Bsrc + (size_t)b*ABSTR + tile*4096 + lane*8)
                       : (Bsrc + (size_t)b*SBSTR + tile*16384 + lane*8);
  }
  const _Float16* Ab[2];
#pragma unroll
  for (int mi=0;mi<MFR;mi++)
    Ab[mi] = A + (size_t)(w*MFR+mi)*((size_t)NSTEP*512) + lane*8;

  f32x16 acc[2][4];
#pragma unroll
  for (int mi=0;mi<MFR;mi++)
#pragma unroll
    for (int nt=0;nt<4;nt++)
#pragma unroll
      for (int r=0;r<16;r++) acc[mi][nt][r] = 0.f;

#define BADDR(nt,s) ((MODE==0) ? (Bb[nt] + (size_t)((s)>>3)*ALSTR + (size_t)((s)&7)*512) \
                               : (Bb[nt] + (size_t)(s)*512))

  f16x8 Ae[2], Ao[2], Be[4], Bo[4];
#pragma unroll
  for (int mi=0;mi<MFR;mi++){
    Ae[mi] = *(const f16x8*)((const void*)(Ab[mi]));
    Ao[mi] = *(const f16x8*)((const void*)(Ab[mi] + 512));
  }
#pragma unroll
  for (int nt=0;nt<4;nt++){
    Be[nt] = *(const f16x8*)((const void*)BADDR(nt,0));
    Bo[nt] = *(const f16x8*)((const void*)BADDR(nt,1));
  }

  for (int s=0; s<NSTEP; s+=2){
#pragma unroll
    for (int mi=0;mi<MFR;mi++)
#pragma unroll
      for (int nt=0;nt<4;nt++)
        acc[mi][nt] = MFMA32(Ae[mi], Be[nt], acc[mi][nt]);
    if (s+2 < NSTEP){
#pragma unroll
      for (int mi=0;mi<MFR;mi++) Ae[mi] = *(const f16x8*)((const void*)(Ab[mi] + (size_t)(s+2)*512));
#pragma unroll
      for (int nt=0;nt<4;nt++)   Be[nt] = *(const f16x8*)((const void*)BADDR(nt,s+2));
    }
#pragma unroll
    for (int mi=0;mi<MFR;mi++)
#pragma unroll
      for (int nt=0;nt<4;nt++)
        acc[mi][nt] = MFMA32(Ao[mi], Bo[nt], acc[mi][nt]);
    if (s+3 < NSTEP){
#pragma unroll
      for (int mi=0;mi<MFR;mi++) Ao[mi] = *(const f16x8*)((const void*)(Ab[mi] + (size_t)(s+3)*512));
#pragma unroll
      for (int nt=0;nt<4;nt++)   Bo[nt] = *(const f16x8*)((const void*)BADDR(nt,s+3));
    }
  }
#undef BADDR

  // ---- epilogue
  if (MODE != 2){
    _Float16* __restrict__ dstb = ((MODE==0)?g_skipF:g_h1F) + (size_t)b*SBSTR;
#pragma unroll
    for (int mi=0; mi<MFR; mi++){
      int mtile = w*MFR+mi;
#pragma unroll
      for (int nt=0; nt<4; nt++){
        int ts = ts0 + nt*32 + ln2;
        if (ts >= FOUT_) continue;
#pragma unroll
        for (int rq=0; rq<4; rq++){
          int m0 = mtile*32 + rq*8 + 4*h;
          union { _Float16 hh[4]; ushort4 v; } pk;
#pragma unroll
          for (int rr=0; rr<4; rr++){
            float vv = acc[mi][nt][rq*4+rr];
            if (MODE==0) vv += g_bssum[m0+rr];
            pk.hh[rr] = (_Float16)fmaxf(vv, 0.f);
          }
          size_t addr = (size_t)(ts>>5)*16384 + (size_t)(mtile*2 + (rq>>1))*512
                      + ((rq&1)*32 + (ts&31))*8 + 4*h;
          *(ushort4*)((void*)(dstb + addr)) = pk.v;
        }
      }
    }
  } else {
#pragma unroll
    for (int nt=0; nt<4; nt++){
      int ts = ts0 + nt*32 + ln2;
      if (ts >= FOUT_) continue;
#pragma unroll
      for (int rq=0; rq<4; rq++){
        int m0 = w*32 + rq*8 + 4*h;
#pragma unroll
        for (int rr=0; rr<4; rr++)
          outF[((size_t)(b*256 + m0 + rr))*FOUT_ + ts] = acc[0][nt][rq*4+rr];
      }
    }
  }
}

// ---------------- host launch ----------------
extern "C" void kernel_launch(void* const* d_in, const int* in_sizes, int n_in,
                              void* d_out, int out_size, void* d_ws, size_t ws_size,
                              hipStream_t stream) {
  const int*   y     = (const int*)  d_in[0];
  const float* embed = (const float*)d_in[1];
  const float* Wd    = (const float*)d_in[2];
  const float* bd    = (const float*)d_in[3];
  const float* Ws    = (const float*)d_in[4];
  const float* bs    = (const float*)d_in[5];
  const float* Wr    = (const float*)d_in[6];
  const float* br    = (const float*)d_in[7];
  const float* W1    = (const float*)d_in[8];
  const float* W2    = (const float*)d_in[9];
  float* out = (float*)d_out;
  (void)d_ws; (void)ws_size;

  cvt_wd<<<dim3(320), dim3(256), 0, stream>>>(Wd);
  cvt_rm<<<dim3(160), dim3(256), 0, stream>>>(Wr, 0, NL_*128, 128);
  cvt_rm<<<dim3(128), dim3(256), 0, stream>>>(W1, 1, 512, 512);
  cvt_rm<<<dim3( 64), dim3(256), 0, stream>>>(W2, 2, 256, 512);
  cvt_ws<<<dim3(640), dim3(256), 0, stream>>>(Ws);
  bssum_k<<<dim3(1), dim3(512), 0, stream>>>(bs);

  embed_kernel<<<dim3((B_*T_*16)/256), dim3(256), 0, stream>>>(y, embed);

  static const int DIL[NL_] = {1,2,4,8,16,32,64,128,256,512,
                               1,2,4,8,16,32,64,128,256,512};
  int swap = 0;
  int Tin = T_;
  for (int i=0;i<NL_;i++){
    int d = DIL[i];
    int Tout = Tin - d;
    dim3 grid((Tout+63)/64, B_);
    layer16<<<grid, dim3(256), 0, stream>>>(
        swap, i, d, Tout, Tout - FOUT_, bd + (size_t)i*256, br + (size_t)i*128);
    swap ^= 1;
    Tin = Tout;
  }

  dim3 gg(FOUTP/128, B_);   // 113 x 4
  gemm_stream<0><<<gg, dim3(512), 0, stream>>>(nullptr);
  gemm_stream<1><<<gg, dim3(512), 0, stream>>>(nullptr);
  gemm_stream<2><<<gg, dim3(512), 0, stream>>>(out);
}